// Round 14
// baseline (706.369 us; speedup 1.0000x reference)
//
#include <hip/hip_runtime.h>
#include <cstdint>
#include <cstddef>

#define NN   10000
#define EE   40000
#define DIN_ 11
#define DD   64
#define LL   4
#define BB   512
#define MM   3
#define K1   128   // 2*D
#define DD2  4096  // D*D
#define NPB  16    // nodes per k_conv block
#define CSPL 2     // chunk-split across blocks
#define CPB  4     // chunks per block
#define ESLOT 12   // register-accumulated edge slots per wave (contiguous)
#define ECREG (8 * ESLOT)  // 96 register-tracked edges per block
#define GSTR 512   // per-m Gp stride (words)

typedef unsigned short ushort_t;
typedef unsigned int   uint_t;

typedef __bf16 bf16x8_t __attribute__((ext_vector_type(8)));
typedef float  f32x4_t  __attribute__((ext_vector_type(4)));
union FragU { uint4 u; bf16x8_t b; };

__device__ __forceinline__ float bfu(ushort_t u) { return __uint_as_float(((uint_t)u) << 16); }
__device__ __forceinline__ float bflo(uint_t u) { return __uint_as_float(u << 16); }
__device__ __forceinline__ float bfhi(uint_t u) { return __uint_as_float(u & 0xffff0000u); }
__device__ __forceinline__ ushort_t f2bf(float f) {
  uint_t u = __float_as_uint(f);
  u = (u + 0x7fffu + ((u >> 16) & 1u)) >> 16;
  return (ushort_t)u;
}
__device__ __forceinline__ uint_t pack2(float lo, float hi) {
  return (uint_t)f2bf(lo) | ((uint_t)f2bf(hi) << 16);
}
__device__ __forceinline__ float sigmf_(float x) { return 1.f / (1.f + expf(-x)); }
__device__ __forceinline__ float siluf_(float x) { return x / (1.f + expf(-x)); }

#if defined(__HIP_DEVICE_COMPILE__) && __has_builtin(__builtin_amdgcn_fdot2_f32_bf16)
typedef __bf16 bf16x2_t __attribute__((ext_vector_type(2)));
__device__ __forceinline__ float dot2a(uint_t a, uint_t b, float c) {
  union { uint_t u; bf16x2_t v; } ua, ub;
  ua.u = a; ub.u = b;
  return __builtin_amdgcn_fdot2_f32_bf16(ua.v, ub.v, c, false);
}
#else
__device__ __forceinline__ float dot2a(uint_t a, uint_t b, float c) {
  return c + bflo(a) * bflo(b) + bfhi(a) * bfhi(b);
}
#endif

// ---- wave-level dtype detect: edge_attr is uniform[0,1). Deterministic, no barrier.
__device__ __forceinline__ int detect_bf16(const void* ea) {
  const int lane = threadIdx.x & 63;
  uint_t v = ((const uint_t*)ea)[lane];
  ushort_t a = (ushort_t)(v & 0xffffu), b = (ushort_t)(v >> 16);
  bool bad = (a & 0x8000u) || a > 0x3F80u || (b & 0x8000u) || b > 0x3F80u;
  return __ballot(bad) == 0ull ? 1 : 0;
}
__device__ __forceinline__ float ldf(const void* p, size_t i, int isbf) {
  return isbf ? bfu(((const ushort_t*)p)[i]) : ((const float*)p)[i];
}

// canon buffer layout (fp32, concatenated)
#define CO_ROOT 0
#define CO_BN2  16384
#define CO_CB   20480
#define CO_WN1  20736
#define CO_BN1  21248
#define CO_LB   21376
#define CO_WO1  21632
#define CO_BO1  29824
#define CO_WO2  29888
#define CO_BO2  29952
#define CO_TOT  29953

// ---------------- fused prep kernel ----------------
// bx [0,128): Wn2 repack. [128,256): LSTM wT. [256,2756): embed (4 nodes/blk, h only).
// [2756,2913): histogram. [2913,3031): canon -> fp32 concat buffer.
#define PB_EMB0 256
#define PB_HIST0 (PB_EMB0 + NN / 4)
#define PB_CAN0 (PB_HIST0 + (EE + 255) / 256)
#define PB_TOTAL (PB_CAN0 + (CO_TOT + 255) / 256)
__global__ __launch_bounds__(256) void k_prep(
    const void* __restrict__ ea, const void* __restrict__ Wn2, uint_t* __restrict__ wn2m,
    const void* __restrict__ Wih, const void* __restrict__ Whh,
    float* __restrict__ Wiht, float* __restrict__ Whht,
    const void* __restrict__ x, const void* __restrict__ W0, const void* __restrict__ b0,
    float* __restrict__ h,
    const int* __restrict__ ei, int* __restrict__ cnt_s,
    const void* __restrict__ root, const void* __restrict__ bn2, const void* __restrict__ cb,
    const void* __restrict__ Wn1, const void* __restrict__ bn1,
    const void* __restrict__ lb, const void* __restrict__ Wo1, const void* __restrict__ bo1,
    const void* __restrict__ Wo2, const void* __restrict__ bo2,
    float* __restrict__ canonbuf) {
  __shared__ ushort_t row[DD2];        // 8 KB (wn2m role)
  __shared__ float xs4[4][DIN_];       // embed role
  const int bx = blockIdx.x, tid = threadIdx.x;
  const int isbf = detect_bf16(ea);

  if (bx < 128) {
    const int k = bx;
    if (isbf) {
      const uint4* src = (const uint4*)((const ushort_t*)Wn2 + (size_t)k * DD2);
      ((uint4*)row)[tid] = src[tid];
      ((uint4*)row)[tid + 256] = src[tid + 256];
    } else {
      const float* src = (const float*)Wn2 + (size_t)k * DD2;
      for (int j = 0; j < 16; ++j) row[tid + 256 * j] = f2bf(src[tid + 256 * j]);
    }
    __syncthreads();
    const int kpg = k >> 1, par = k & 1;
    const int lane = tid >> 2, jp = tid & 3;
    const int q = lane >> 4, n = lane & 15;
    for (int fc = 0; fc < 4; ++fc) {
#pragma unroll
      for (int hf = 0; hf < 2; ++hf) {
        int d0 = hf * 32 + q * 8 + 2 * jp;
        int f = fc * 16 + n;
        uint_t lo = row[d0 * 64 + f], hi = row[(d0 + 1) * 64 + f];
        wn2m[((((size_t)kpg * 4 + fc) * 2 + par) * 2 + hf) * 256 + tid] = lo | (hi << 16);
      }
    }
  } else if (bx < PB_EMB0) {
    int idx = (bx - 128) * 256 + tid;
    {
      int j = idx >> 7, i = idx & 127;
      Wiht[i * 256 + j] = ldf(Wih, idx, isbf);
    }
    if (idx < 4 * DD * DD) {
      int j = idx >> 6, i = idx & 63;
      Whht[i * 256 + j] = ldf(Whh, idx, isbf);
    }
  } else if (bx < PB_HIST0) {
    const int w = tid >> 6, f = tid & 63;
    const int n = (bx - PB_EMB0) * 4 + w;
    if (f < DIN_) xs4[w][f] = ldf(x, (size_t)n * DIN_ + f, isbf);
    __syncthreads();
    float a = ldf(b0, f, isbf);
    for (int i = 0; i < DIN_; ++i) a += xs4[w][i] * ldf(W0, i * DD + f, isbf);
    h[(size_t)n * DD + f] = a;
  } else if (bx < PB_CAN0) {
    int e = (bx - PB_HIST0) * 256 + tid;
    if (e < EE) atomicAdd(&cnt_s[ei[e]], 1);
  } else {
    int idx = (bx - PB_CAN0) * 256 + tid;
    const void* src; int base;
    if      (idx < CO_BN2) { src = root; base = CO_ROOT; }
    else if (idx < CO_CB)  { src = bn2;  base = CO_BN2; }
    else if (idx < CO_WN1) { src = cb;   base = CO_CB; }
    else if (idx < CO_BN1) { src = Wn1;  base = CO_WN1; }
    else if (idx < CO_LB)  { src = bn1;  base = CO_BN1; }
    else if (idx < CO_WO1) { src = lb;   base = CO_LB; }
    else if (idx < CO_BO1) { src = Wo1;  base = CO_WO1; }
    else if (idx < CO_WO2) { src = bo1;  base = CO_BO1; }
    else if (idx < CO_BO2) { src = Wo2;  base = CO_WO2; }
    else if (idx < CO_TOT) { src = bo2;  base = CO_BO2; }
    else return;
    canonbuf[idx] = ldf(src, idx - base, isbf);
  }
}

// block 0: exclusive scan of cnt -> rp; block 1: goff from sorted batch
__global__ void k_scan(const int* __restrict__ cnt, int* __restrict__ rp,
                       const int* __restrict__ batch, int* __restrict__ goff) {
  if (blockIdx.x == 1) {
    int g = threadIdx.x;
    if (g > BB) return;
    int lo = 0, hi = NN;
    while (lo < hi) {
      int mid = (lo + hi) >> 1;
      if (batch[mid] < g) lo = mid + 1; else hi = mid;
    }
    goff[g] = lo;
    return;
  }
  __shared__ int part[1024];
  const int tid = threadIdx.x;
  const int chunk = (NN + 1023) / 1024;
  int s = 0;
  for (int j = 0; j < chunk; ++j) {
    int idx = tid * chunk + j;
    if (idx < NN) s += cnt[idx];
  }
  part[tid] = s;
  __syncthreads();
  for (int off = 1; off < 1024; off <<= 1) {
    int v = (tid >= off) ? part[tid - off] : 0;
    __syncthreads();
    part[tid] += v;
    __syncthreads();
  }
  int base = (tid == 0) ? 0 : part[tid - 1];
  for (int j = 0; j < chunk; ++j) {
    int idx = tid * chunk + j;
    if (idx < NN) { rp[idx] = base; base += cnt[idx]; }
  }
  if (tid == 1023) rp[NN] = part[1023];
}

// epos[e] = CSR slot of edge e; esd[2*pos..] = (src, dst)
__global__ void k_fill(const int* __restrict__ ei, const int* __restrict__ rps,
                       int* __restrict__ cur_s, int* __restrict__ epos,
                       int* __restrict__ esd) {
  int e = blockIdx.x * 256 + threadIdx.x;
  if (e >= EE) return;
  int s = ei[e], d = ei[EE + e];
  int ps = atomicAdd(&cur_s[s], 1);
  int pos = rps[s] + ps;
  epos[e] = pos;
  esd[2 * pos] = s;
  esd[2 * pos + 1] = d;
}

// ---------------- edge MLP layer1 -> hn1c, chunk-major CSR order ----------------
__global__ void k_edgemlp(const void* __restrict__ ea, const float* __restrict__ Wn1,
                          const float* __restrict__ bn1, const int* __restrict__ epos,
                          uint_t* __restrict__ hn1c) {
  const int isbf = detect_bf16(ea);
  int idx = blockIdx.x * 256 + threadIdx.x;  // e*64 + j
  if (idx >= EE * (K1 / 2)) return;
  int e = idx >> 6, j = idx & 63;
  int k0 = 2 * j, k1 = 2 * j + 1;
  float a0 = ldf(ea, e * 4 + 0, isbf), a1 = ldf(ea, e * 4 + 1, isbf);
  float a2 = ldf(ea, e * 4 + 2, isbf), a3 = ldf(ea, e * 4 + 3, isbf);
  float t0 = bn1[k0] + a0 * Wn1[k0] + a1 * Wn1[K1 + k0] + a2 * Wn1[2 * K1 + k0] + a3 * Wn1[3 * K1 + k0];
  float t1 = bn1[k1] + a0 * Wn1[k1] + a1 * Wn1[K1 + k1] + a2 * Wn1[2 * K1 + k1] + a3 * Wn1[3 * K1 + k1];
  int pos = epos[e];
  hn1c[((size_t)(j >> 3) * EE + pos) * 8 + (j & 7)] = pack2(siluf_(t0), siluf_(t1));
}

// ---------------- fused NNConv kernel (update(l-1) head + message layer l) ----------------
// Grid: CSPL*625. half = bx/625, ng = bx%625. Head: if dofuse, compute this block's
// 16 nodes' layer-(l-1) update (h_l = h_{l-1} + Ar + cb + h_{l-1}@root) entirely from
// hR (ping-pong read buf) -> write hW (ping-pong write buf; both halves dup-write
// identical values), zero Az (3-rotation: no concurrent reader/writer). A-fragments
// and nbias computed block-locally (no global hpk/nbias). Then CPB=4 serial chunks:
// MFMA phase1 -> Gp; phase2 register-resident edge partials; 1 atomic/edge/half -> Aw.
__global__ __launch_bounds__(512, 4) void k_conv(
    const float* __restrict__ hR, float* __restrict__ hW,
    const float* __restrict__ Ar, float* __restrict__ Aw, float* __restrict__ Az,
    const uint_t* __restrict__ hn1c, const uint_t* __restrict__ Wn2m,
    const int* __restrict__ rps, const int* __restrict__ esd,
    const float* __restrict__ rootL, const float* __restrict__ cbL,
    const float* __restrict__ bn2c, int dofuse) {
  __shared__ uint_t Gp[NPB * GSTR];        // 32 KB (head reuses as fp32 scratch)
  __shared__ int2 eStage[ECREG];           // 768 B
  __shared__ float nbiasL[NPB * DD];       // 4 KB persistent
  float* hscr = (float*)Gp;                // [0,1024) h_{l-1}; [1024,2048) h_l
  const int tid = threadIdx.x;
  const int w = tid >> 6, lane = tid & 63;
  const int q = lane >> 4, n16 = lane & 15;
  const int half = blockIdx.x / 625;
  const int ng = blockIdx.x - half * 625;
  const int n0 = ng * NPB;
  const int e0 = rps[n0], e1 = rps[n0 + NPB];
  const int ecnt = e1 - e0;

  if (tid < ECREG && tid < ecnt) eStage[tid] = ((const int2*)esd)[e0 + tid];
  for (int i = tid; i < NPB * DD; i += 512) hscr[i] = hR[(size_t)n0 * DD + i];
  __syncthreads();

  int hlb = 0;
  if (dofuse) {
#pragma unroll
    for (int half2 = 0; half2 < 2; ++half2) {
      const int idx = tid + half2 * 512;       // (n,f): n = idx>>6 wave-uniform
      const int n = idx >> 6, f = idx & 63;
      float v = hscr[idx] + Ar[(size_t)n0 * DD + idx] + cbL[f];
      const float* hp = hscr + n * DD;
#pragma unroll
      for (int d = 0; d < DD; ++d) v += hp[d] * rootL[d * DD + f];
      hscr[1024 + idx] = v;
      hW[(size_t)n0 * DD + idx] = v;
      Az[(size_t)n0 * DD + idx] = 0.f;
    }
    hlb = 1024;
  } else {
#pragma unroll
    for (int half2 = 0; half2 < 2; ++half2)
      Az[(size_t)n0 * DD + tid + half2 * 512] = 0.f;
  }
  __syncthreads();
  // nbias (block-local) + A fragments from hscr[hlb..]
#pragma unroll
  for (int half2 = 0; half2 < 2; ++half2) {
    const int idx = tid + half2 * 512;
    const int n = idx >> 6, f = idx & 63;
    float nb = 0.f;
    const float* hp = hscr + hlb + n * DD;
#pragma unroll
    for (int d = 0; d < DD; ++d) nb += hp[d] * bn2c[d * DD + f];
    nbiasL[idx] = nb;
  }
  FragU a0, a1;
  {
    const float* hp = hscr + hlb + n16 * DD;
    uint_t u0[4], u1[4];
#pragma unroll
    for (int t = 0; t < 4; ++t) {
      u0[t] = pack2(hp[8 * q + 2 * t], hp[8 * q + 2 * t + 1]);
      u1[t] = pack2(hp[32 + 8 * q + 2 * t], hp[32 + 8 * q + 2 * t + 1]);
    }
    a0.u.x = u0[0]; a0.u.y = u0[1]; a0.u.z = u0[2]; a0.u.w = u0[3];
    a1.u.x = u1[0]; a1.u.y = u1[1]; a1.u.z = u1[2]; a1.u.w = u1[3];
  }
  __syncthreads();  // all hscr reads done; nbiasL visible; Gp free for phase1

  float acc[ESLOT];
#pragma unroll
  for (int s = 0; s < ESLOT; ++s) {
    const int li = w * ESLOT + s;
    float v = 0.f;
    if (half == 0 && li < ecnt)
      v = nbiasL[(eStage[li].x - n0) * DD + lane];
    acc[s] = v;
  }

  const int p = w & 3, fh = w >> 2;
  const int wkq = p >> 1, slot2 = (p & 1) * 2;
  for (int cc = 0; cc < CPB; ++cc) {
    const int c = half * CPB + cc;
    if (cc) __syncthreads();
    // ---- phase 1 ----
#pragma unroll
    for (int fi = 0; fi < 2; ++fi) {
      const int fc = fh * 2 + fi;
      uint_t pk[2][4];
#pragma unroll
      for (int kk = 0; kk < 2; ++kk) {
        const int kpg = c * 8 + 2 * p + kk;
        const uint4* bp = (const uint4*)Wn2m + (size_t)(kpg * 4 + fc) * 256 + lane;
        FragU b00, b01, b10, b11;
        b00.u = bp[0];    // par0 hf0
        b01.u = bp[64];   // par0 hf1
        b10.u = bp[128];  // par1 hf0
        b11.u = bp[192];  // par1 hf1
        f32x4_t acc0 = {0.f, 0.f, 0.f, 0.f};
        f32x4_t acc1 = {0.f, 0.f, 0.f, 0.f};
        acc0 = __builtin_amdgcn_mfma_f32_16x16x32_bf16(a0.b, b00.b, acc0, 0, 0, 0);
        acc0 = __builtin_amdgcn_mfma_f32_16x16x32_bf16(a1.b, b01.b, acc0, 0, 0, 0);
        acc1 = __builtin_amdgcn_mfma_f32_16x16x32_bf16(a0.b, b10.b, acc1, 0, 0, 0);
        acc1 = __builtin_amdgcn_mfma_f32_16x16x32_bf16(a1.b, b11.b, acc1, 0, 0, 0);
#pragma unroll
        for (int r = 0; r < 4; ++r)
          pk[kk][r] = pack2(acc0[r], acc1[r]);
      }
#pragma unroll
      for (int r = 0; r < 4; ++r) {
        const int m = q * 4 + r;
        uint2 v; v.x = pk[0][r]; v.y = pk[1][r];
        *(uint2*)&Gp[(size_t)m * GSTR + (wkq * 64 + fc * 16 + n16) * 4 + slot2] = v;
      }
    }
    __syncthreads();
    // ---- phase 2: contiguous slots, src-dedup G reads ----
    int prev_src = -1;
    uint4 g0, g1;
#pragma unroll
    for (int s = 0; s < ESLOT; ++s) {
      const int li = w * ESLOT + s;
      if (li < ecnt) {
        const int2 sd = eStage[li];
        if (sd.x != prev_src) {  // wave-uniform branch
          prev_src = sd.x;
          const uint4* gb = (const uint4*)Gp + (size_t)(prev_src - n0) * (GSTR / 4) + lane;
          g0 = gb[0];
          g1 = gb[64];
        }
        const uint4* hp = (const uint4*)(hn1c + ((size_t)c * EE + e0 + li) * 8);
        uint4 hv0 = hp[0], hv1 = hp[1];
        float pt = acc[s];
        pt = dot2a(g0.x, hv0.x, pt);
        pt = dot2a(g0.y, hv0.y, pt);
        pt = dot2a(g0.z, hv0.z, pt);
        pt = dot2a(g0.w, hv0.w, pt);
        pt = dot2a(g1.x, hv1.x, pt);
        pt = dot2a(g1.y, hv1.y, pt);
        pt = dot2a(g1.z, hv1.z, pt);
        pt = dot2a(g1.w, hv1.w, pt);
        acc[s] = pt;
      }
    }
    // overflow edges (virtually never): per-chunk atomic path
    for (int li = ECREG + w; li < ecnt; li += 8) {
      const int ii = e0 + li;
      const int src = __builtin_amdgcn_readfirstlane(esd[2 * ii]);
      const int dst = __builtin_amdgcn_readfirstlane(esd[2 * ii + 1]);
      const int m = src - n0;
      float pt = (half == 0 && cc == 0) ? nbiasL[m * DD + lane] : 0.f;
      const uint4* hp = (const uint4*)(hn1c + ((size_t)c * EE + ii) * 8);
      uint4 hv0 = hp[0], hv1 = hp[1];
      const uint4* gb = (const uint4*)Gp + (size_t)m * (GSTR / 4) + lane;
      uint4 og0 = gb[0], og1 = gb[64];
      pt = dot2a(og0.x, hv0.x, pt);
      pt = dot2a(og0.y, hv0.y, pt);
      pt = dot2a(og0.z, hv0.z, pt);
      pt = dot2a(og0.w, hv0.w, pt);
      pt = dot2a(og1.x, hv1.x, pt);
      pt = dot2a(og1.y, hv1.y, pt);
      pt = dot2a(og1.z, hv1.z, pt);
      pt = dot2a(og1.w, hv1.w, pt);
      atomicAdd(&Aw[(size_t)dst * DD + lane], pt);
    }
  }
  // ---- commit ----
#pragma unroll
  for (int s = 0; s < ESLOT; ++s) {
    const int li = w * ESLOT + s;
    if (li < ecnt) {
      const int dst = eStage[li].y;
      atomicAdd(&Aw[(size_t)dst * DD + lane], acc[s]);
    }
  }
}

// ---------------- final update (h4 for s2s): 4 nodes/block ----------------
__global__ __launch_bounds__(256) void k_upfin(
    const float* __restrict__ hIn, const float* __restrict__ A,
    const float* __restrict__ rootL, const float* __restrict__ cbL,
    float* __restrict__ hOut) {
  __shared__ float hl[4][DD];
  const int tid = threadIdx.x, w = tid >> 6, f = tid & 63;
  const int n = blockIdx.x * 4 + w;
  float hv = hIn[(size_t)n * DD + f];
  hl[w][f] = hv;
  float acc = hv + A[(size_t)n * DD + f] + cbL[f];
  __syncthreads();
#pragma unroll
  for (int d = 0; d < DD; ++d) acc += hl[w][d] * rootL[d * DD + f];
  hOut[(size_t)n * DD + f] = acc;
}

// ---------------- fused Set2Set (3x LSTM+attention) + output MLP ----------------
#define EVCAP 512
__global__ void k_s2s(const void* __restrict__ ea,
                      const float* __restrict__ h, const int* __restrict__ goff,
                      const float* __restrict__ Wiht, const float* __restrict__ Whht,
                      const float* __restrict__ lb,
                      const float* __restrict__ Wo1, const float* __restrict__ bo1,
                      const float* __restrict__ Wo2, const float* __restrict__ bo2,
                      void* __restrict__ outv) {
  __shared__ float qsl[K1];
  __shared__ float hsl[DD];
  __shared__ float csl[DD];
  __shared__ float gl[4][DD];
  __shared__ float red[256];
  __shared__ float ev[EVCAP];
  __shared__ float rp4[4][DD];
  const int isbf = detect_bf16(ea);
  const int g = blockIdx.x, tid = threadIdx.x;

  if (tid < K1) qsl[tid] = 0.f;
  else if (tid < K1 + DD) hsl[tid - K1] = 0.f;
  else csl[tid - K1 - DD] = 0.f;
  __syncthreads();

  const int i0 = goff[g];
  int cnt = goff[g + 1] - i0;
  if (cnt > EVCAP) cnt = EVCAP;  // never triggers (mean 19.5/graph)

  for (int m = 0; m < MM; ++m) {
    {
      float a = lb[tid];
      for (int i = 0; i < K1; ++i) a += qsl[i] * Wiht[i * 256 + tid];
      for (int i = 0; i < DD; ++i) a += hsl[i] * Whht[i * 256 + tid];
      gl[tid >> 6][tid & 63] = a;
    }
    __syncthreads();
    if (tid < DD) {
      float ig = sigmf_(gl[0][tid]), fg = sigmf_(gl[1][tid]);
      float gg = tanhf(gl[2][tid]), og = sigmf_(gl[3][tid]);
      float c = fg * csl[tid] + ig * gg;
      csl[tid] = c;
      hsl[tid] = og * tanhf(c);
    }
    __syncthreads();
    float lmax = -1e30f;
    for (int jj = tid; jj < cnt; jj += 256) {
      const float* hp = h + (size_t)(i0 + jj) * DD;
      float e = 0.f;
#pragma unroll
      for (int d = 0; d < DD; ++d) e += hp[d] * hsl[d];
      ev[jj] = e;
      lmax = fmaxf(lmax, e);
    }
    red[tid] = lmax;
    __syncthreads();
    for (int s = 128; s > 0; s >>= 1) {
      if (tid < s) red[tid] = fmaxf(red[tid], red[tid + s]);
      __syncthreads();
    }
    const float emax = red[0];
    __syncthreads();
    float lsum = 0.f;
    for (int jj = tid; jj < cnt; jj += 256) {
      float ex = expf(ev[jj] - emax);
      ev[jj] = ex;
      lsum += ex;
    }
    red[tid] = lsum;
    __syncthreads();
    for (int s = 128; s > 0; s >>= 1) {
      if (tid < s) red[tid] += red[tid + s];
      __syncthreads();
    }
    const float denom = red[0];
    const int f = tid & 63, grp = tid >> 6;
    float acc = 0.f;
    for (int jj = grp; jj < cnt; jj += 4)
      acc += ev[jj] * h[(size_t)(i0 + jj) * DD + f];
    rp4[grp][f] = acc;
    __syncthreads();
    if (tid < DD) {
      float r = rp4[0][tid] + rp4[1][tid] + rp4[2][tid] + rp4[3][tid];
      r = (cnt > 0 && denom > 0.f) ? r / denom : 0.f;
      qsl[tid] = hsl[tid];
      qsl[DD + tid] = r;
    }
    __syncthreads();
  }
  if (tid < DD) {
    float t = bo1[tid];
    for (int i = 0; i < K1; ++i) t += qsl[i] * Wo1[i * DD + tid];
    float s = siluf_(t) * Wo2[tid];
    for (int off = 32; off > 0; off >>= 1) s += __shfl_down(s, off);
    if (tid == 0) {
      float v = s + bo2[0];
      if (isbf) ((ushort_t*)outv)[g] = f2bf(v);
      else      ((float*)outv)[g] = v;
    }
  }
}

extern "C" void kernel_launch(void* const* d_in, const int* in_sizes, int n_in,
                              void* d_out, int out_size, void* d_ws, size_t ws_size,
                              hipStream_t stream) {
  const void* x_r    = d_in[0];
  const int*  ei     = (const int*)d_in[1];
  const void* ea_r   = d_in[2];
  const int*  batch  = (const int*)d_in[3];
  const void* W0_r   = d_in[4];
  const void* b0_r   = d_in[5];
  const void* Wn1_r  = d_in[6];
  const void* bn1_r  = d_in[7];
  const void* Wn2_r  = d_in[8];
  const void* bn2_r  = d_in[9];
  const void* root_r = d_in[10];
  const void* cb_r   = d_in[11];
  const void* Wih_r  = d_in[12];
  const void* Whh_r  = d_in[13];
  const void* lb_r   = d_in[14];
  const void* Wo1_r  = d_in[15];
  const void* bo1_r  = d_in[16];
  const void* Wo2_r  = d_in[17];
  const void* bo2_r  = d_in[18];

  char* w = (char*)d_ws;
  size_t off = 0;
  auto alloc = [&](size_t bytes) -> void* {
    void* p = w + off;
    off = (off + bytes + 255) & ~(size_t)255;
    return p;
  };
  float* Wiht  = (float*)alloc((size_t)K1 * 256 * 4);
  float* Whht  = (float*)alloc((size_t)DD * 256 * 4);
  float* canon = (float*)alloc((size_t)CO_TOT * 4);
  uint_t* Wn2m = (uint_t*)alloc((size_t)64 * 4 * 2 * 2 * 64 * 4 * 4);  // 1 MB
  float*  hb0  = (float*)alloc((size_t)NN * DD * 4);
  float*  hb1  = (float*)alloc((size_t)NN * DD * 4);
  uint_t* hn1c = (uint_t*)alloc((size_t)EE * (K1 / 2) * 4);  // chunk-major
  float*  A0   = (float*)alloc((size_t)NN * DD * 4);
  float*  A1   = (float*)alloc((size_t)NN * DD * 4);
  float*  A2   = (float*)alloc((size_t)NN * DD * 4);
  int* cnts  = (int*)alloc((size_t)2 * NN * 4);
  int* rps   = (int*)alloc((size_t)(NN + 1) * 4);
  int* epos  = (int*)alloc((size_t)EE * 4);
  int* esd   = (int*)alloc((size_t)2 * EE * 4);
  int* goff  = (int*)alloc((size_t)(BB + 1) * 4);

  int* cnt_s = cnts;
  int* cur_s = cnts + NN;

  float* rootc = canon + CO_ROOT;
  float* bn2c  = canon + CO_BN2;
  float* cbc   = canon + CO_CB;
  float* Wn1c  = canon + CO_WN1;
  float* bn1c  = canon + CO_BN1;
  float* lbc   = canon + CO_LB;
  float* Wo1c  = canon + CO_WO1;
  float* bo1c  = canon + CO_BO1;
  float* Wo2c  = canon + CO_WO2;
  float* bo2c  = canon + CO_BO2;

  hipMemsetAsync(cnts, 0, (size_t)2 * NN * 4, stream);
  hipMemsetAsync(A0, 0, (size_t)3 * NN * DD * 4, stream);  // A0,A1,A2 contiguous

  k_prep<<<PB_TOTAL, 256, 0, stream>>>(
      ea_r, Wn2_r, Wn2m, Wih_r, Whh_r, Wiht, Whht,
      x_r, W0_r, b0_r, hb0, ei, cnt_s,
      root_r, bn2_r, cb_r, Wn1_r, bn1_r, lb_r, Wo1_r, bo1_r, Wo2_r, bo2_r, canon);
  k_scan<<<2, 1024, 0, stream>>>(cnt_s, rps, batch, goff);
  k_fill<<<(EE + 255) / 256, 256, 0, stream>>>(ei, rps, cur_s, epos, esd);
  k_edgemlp<<<(EE * (K1 / 2) + 255) / 256, 256, 0, stream>>>(ea_r, Wn1c, bn1c, epos, hn1c);

  // conv(l): head fuses update(l-1). Ping-pong h; triple-rotate A.
  // conv0: read hb0 (h0), atomics->A0, zero A1.
  k_conv<<<CSPL * (NN / NPB), 512, 0, stream>>>(hb0, hb1, A0, A0, A1, hn1c, Wn2m,
                                                rps, esd, rootc, cbc, bn2c, 0);
  // conv1: h1 = upd(h0, A0, root0); write hb1; atomics->A1; zero A2.
  k_conv<<<CSPL * (NN / NPB), 512, 0, stream>>>(hb0, hb1, A0, A1, A2, hn1c, Wn2m,
                                                rps, esd, rootc, cbc, bn2c, 1);
  // conv2: h2 = upd(h1, A1, root1); write hb0; atomics->A2; zero A0.
  k_conv<<<CSPL * (NN / NPB), 512, 0, stream>>>(hb1, hb0, A1, A2, A0, hn1c, Wn2m,
                                                rps, esd, rootc + DD2, cbc + DD, bn2c, 1);
  // conv3: h3 = upd(h2, A2, root2); write hb1; atomics->A0; zero A1.
  k_conv<<<CSPL * (NN / NPB), 512, 0, stream>>>(hb0, hb1, A2, A0, A1, hn1c, Wn2m,
                                                rps, esd, rootc + 2 * DD2, cbc + 2 * DD, bn2c, 1);
  // h4 = upd(h3, A0, root3) -> hb0
  k_upfin<<<NN / 4, 256, 0, stream>>>(hb1, A0, rootc + 3 * DD2, cbc + 3 * DD, hb0);

  k_s2s<<<BB, 256, 0, stream>>>(ea_r, hb0, goff, Wiht, Whht, lbc, Wo1c, bo1c, Wo2c,
                                bo2c, d_out);
}

// Round 15
// 483.684 us; speedup vs baseline: 1.4604x; 1.4604x over previous
//
#include <hip/hip_runtime.h>
#include <cstdint>
#include <cstddef>

#define NN   10000
#define EE   40000
#define DIN_ 11
#define DD   64
#define LL   4
#define BB   512
#define MM   3
#define K1   128   // 2*D
#define DD2  4096  // D*D
#define NPB  16    // nodes per k_conv block
#define CSPL 2     // chunk-split across blocks
#define CPB  4     // chunks per block
#define ESLOT 12   // register-accumulated edge slots per wave (contiguous)
#define ECREG (8 * ESLOT)  // 96 register-tracked edges per block
#define GSTR 512   // per-m Gp stride (words)

typedef unsigned short ushort_t;
typedef unsigned int   uint_t;

typedef __bf16 bf16x8_t __attribute__((ext_vector_type(8)));
typedef float  f32x4_t  __attribute__((ext_vector_type(4)));
union FragU { uint4 u; bf16x8_t b; };

__device__ __forceinline__ float bfu(ushort_t u) { return __uint_as_float(((uint_t)u) << 16); }
__device__ __forceinline__ float bflo(uint_t u) { return __uint_as_float(u << 16); }
__device__ __forceinline__ float bfhi(uint_t u) { return __uint_as_float(u & 0xffff0000u); }
__device__ __forceinline__ ushort_t f2bf(float f) {
  uint_t u = __float_as_uint(f);
  u = (u + 0x7fffu + ((u >> 16) & 1u)) >> 16;
  return (ushort_t)u;
}
__device__ __forceinline__ uint_t pack2(float lo, float hi) {
  return (uint_t)f2bf(lo) | ((uint_t)f2bf(hi) << 16);
}
__device__ __forceinline__ float sigmf_(float x) { return 1.f / (1.f + expf(-x)); }
__device__ __forceinline__ float siluf_(float x) { return x / (1.f + expf(-x)); }

#if defined(__HIP_DEVICE_COMPILE__) && __has_builtin(__builtin_amdgcn_fdot2_f32_bf16)
typedef __bf16 bf16x2_t __attribute__((ext_vector_type(2)));
__device__ __forceinline__ float dot2a(uint_t a, uint_t b, float c) {
  union { uint_t u; bf16x2_t v; } ua, ub;
  ua.u = a; ub.u = b;
  return __builtin_amdgcn_fdot2_f32_bf16(ua.v, ub.v, c, false);
}
#else
__device__ __forceinline__ float dot2a(uint_t a, uint_t b, float c) {
  return c + bflo(a) * bflo(b) + bfhi(a) * bfhi(b);
}
#endif

// ---------------- canonicalize float inputs to fp32 (self-detecting dtype) ----------------
#define NCANON 16
struct CanonArgs {
  const void* src[NCANON];
  float* dst[NCANON];
  int n[NCANON];
};
__global__ void k_canon(CanonArgs a, const ushort_t* __restrict__ ea, int* __restrict__ flag) {
  __shared__ int bad;
  if (threadIdx.x == 0) bad = 0;
  __syncthreads();
  ushort_t u = ea[threadIdx.x];
  if ((u & 0x8000u) || u > 0x3F80u) atomicAdd(&bad, 1);
  __syncthreads();
  const int isbf = (bad == 0) ? 1 : 0;
  if (blockIdx.x == 0 && blockIdx.y == 0 && threadIdx.x == 0) *flag = isbf;
  const int ai = blockIdx.y;
  const int n = a.n[ai];
  const int i = blockIdx.x * 256 + threadIdx.x;
  if (i >= n) return;
  float v;
  if (isbf) v = bfu(((const ushort_t*)a.src[ai])[i]);
  else      v = ((const float*)a.src[ai])[i];
  a.dst[ai][i] = v;
}

// ---------------- Wn2 repack into MFMA B-fragment order (coalesced) ----------------
__global__ void k_wn2m(const void* __restrict__ Wn2, uint_t* __restrict__ out,
                       const int* __restrict__ flag) {
  __shared__ ushort_t row[DD2];  // 8 KB
  const int k = blockIdx.x, tid = threadIdx.x;
  if (*flag) {
    const uint4* src = (const uint4*)((const ushort_t*)Wn2 + (size_t)k * DD2);
    ((uint4*)row)[tid] = src[tid];
    ((uint4*)row)[tid + 256] = src[tid + 256];
  } else {
    const float* src = (const float*)Wn2 + (size_t)k * DD2;
    for (int j = 0; j < 16; ++j) row[tid + 256 * j] = f2bf(src[tid + 256 * j]);
  }
  __syncthreads();
  const int kpg = k >> 1, par = k & 1;
  const int lane = tid >> 2, jp = tid & 3;
  const int q = lane >> 4, n = lane & 15;
  for (int fc = 0; fc < 4; ++fc) {
#pragma unroll
    for (int hf = 0; hf < 2; ++hf) {
      int d0 = hf * 32 + q * 8 + 2 * jp;
      int f = fc * 16 + n;
      uint_t lo = row[d0 * 64 + f], hi = row[(d0 + 1) * 64 + f];
      out[((((size_t)kpg * 4 + fc) * 2 + par) * 2 + hf) * 256 + tid] = lo | (hi << 16);
    }
  }
}

// ---------------- LSTM weight transpose: Wiht[i][j], Whht[i][j] ----------------
__global__ void k_wT(const float* __restrict__ Wihc, const float* __restrict__ Whhc,
                     float* __restrict__ Wiht, float* __restrict__ Whht) {
  int idx = blockIdx.x * 256 + threadIdx.x;
  if (idx < 4 * DD * K1) {
    int j = idx >> 7, i = idx & 127;  // Wihc[j][i]
    Wiht[i * 256 + j] = Wihc[idx];
  }
  if (idx < 4 * DD * DD) {
    int j = idx >> 6, i = idx & 63;   // Whhc[j][i]
    Whht[i * 256 + j] = Whhc[idx];
  }
}

// ---------------- node embed: 4 nodes/block; h, hpk, nbias ----------------
__global__ __launch_bounds__(256) void k_embed(
    const float* __restrict__ x, const float* __restrict__ W0,
    const float* __restrict__ b0, const float* __restrict__ bn2,
    float* __restrict__ h, uint_t* __restrict__ hpk, float* __restrict__ nbias) {
  __shared__ float xs4[4][DIN_];
  __shared__ float hl4[4][DD];
  const int tid = threadIdx.x, w = tid >> 6, f = tid & 63;
  const int n = blockIdx.x * 4 + w;
  if (f < DIN_) xs4[w][f] = x[(size_t)n * DIN_ + f];
  __syncthreads();
  float a = b0[f];
  for (int i = 0; i < DIN_; ++i) a += xs4[w][i] * W0[i * DD + f];
  h[(size_t)n * DD + f] = a;
  hl4[w][f] = a;
  float other = __shfl_down(a, 1);
  if ((f & 1) == 0)
    hpk[(size_t)n * 32 + (f >> 1)] = pack2(a, other);
  __syncthreads();
  float nb = 0.f;
#pragma unroll
  for (int d = 0; d < DD; ++d) nb += hl4[w][d] * bn2[d * DD + f];
  nbias[(size_t)n * DD + f] = nb;
}

// ---------------- edge MLP layer1 -> hn1c, chunk-major CSR order ----------------
__global__ void k_edgemlp(const float* __restrict__ ea, const float* __restrict__ Wn1,
                          const float* __restrict__ bn1, const int* __restrict__ epos,
                          uint_t* __restrict__ hn1c) {
  int idx = blockIdx.x * 256 + threadIdx.x;  // e*64 + j
  if (idx >= EE * (K1 / 2)) return;
  int e = idx >> 6, j = idx & 63;
  int k0 = 2 * j, k1 = 2 * j + 1;
  float a0 = ea[e * 4 + 0], a1 = ea[e * 4 + 1], a2 = ea[e * 4 + 2], a3 = ea[e * 4 + 3];
  float t0 = bn1[k0] + a0 * Wn1[k0] + a1 * Wn1[K1 + k0] + a2 * Wn1[2 * K1 + k0] + a3 * Wn1[3 * K1 + k0];
  float t1 = bn1[k1] + a0 * Wn1[k1] + a1 * Wn1[K1 + k1] + a2 * Wn1[2 * K1 + k1] + a3 * Wn1[3 * K1 + k1];
  int pos = epos[e];
  hn1c[((size_t)(j >> 3) * EE + pos) * 8 + (j & 7)] = pack2(siluf_(t0), siluf_(t1));
}

// ---------------- src-CSR build ----------------
__global__ void k_hist(const int* __restrict__ ei, int* __restrict__ cnt_s) {
  int e = blockIdx.x * 256 + threadIdx.x;
  if (e >= EE) return;
  atomicAdd(&cnt_s[ei[e]], 1);
}

// block 0: exclusive scan of cnt -> rp; block 1: goff from sorted batch
__global__ void k_scan(const int* __restrict__ cnt, int* __restrict__ rp,
                       const int* __restrict__ batch, int* __restrict__ goff) {
  if (blockIdx.x == 1) {
    int g = threadIdx.x;
    if (g > BB) return;
    int lo = 0, hi = NN;
    while (lo < hi) {
      int mid = (lo + hi) >> 1;
      if (batch[mid] < g) lo = mid + 1; else hi = mid;
    }
    goff[g] = lo;
    return;
  }
  __shared__ int part[1024];
  const int tid = threadIdx.x;
  const int chunk = (NN + 1023) / 1024;
  int s = 0;
  for (int j = 0; j < chunk; ++j) {
    int idx = tid * chunk + j;
    if (idx < NN) s += cnt[idx];
  }
  part[tid] = s;
  __syncthreads();
  for (int off = 1; off < 1024; off <<= 1) {
    int v = (tid >= off) ? part[tid - off] : 0;
    __syncthreads();
    part[tid] += v;
    __syncthreads();
  }
  int base = (tid == 0) ? 0 : part[tid - 1];
  for (int j = 0; j < chunk; ++j) {
    int idx = tid * chunk + j;
    if (idx < NN) { rp[idx] = base; base += cnt[idx]; }
  }
  if (tid == 1023) rp[NN] = part[1023];
}

// epos[e] = CSR slot of edge e; esd[2*pos..] = (src, dst)
__global__ void k_fill(const int* __restrict__ ei, const int* __restrict__ rps,
                       int* __restrict__ cur_s, int* __restrict__ epos,
                       int* __restrict__ esd) {
  int e = blockIdx.x * 256 + threadIdx.x;
  if (e >= EE) return;
  int s = ei[e], d = ei[EE + e];
  int ps = atomicAdd(&cur_s[s], 1);
  int pos = rps[s] + ps;
  epos[e] = pos;
  esd[2 * pos] = s;
  esd[2 * pos + 1] = d;
}

// ---------------- fused NNConv message kernel (R13 variant: b64 writes, src-dedup) ----------------
// Grid: CSPL*625, 512 threads. half = bx/625, ng = bx%625. Block serializes CPB=4
// chunks of 8 kp. Phase 1: p = w&3 owns kp pair {2p,2p+1}, fh = w>>2 owns fc half;
// b64 LDS writes. Phase 2: wave w owns CSR-contiguous edge slots [12w,12w+12);
// G regs reloaded only on src change. One atomicAdd per edge per half at the end.
__global__ __launch_bounds__(512, 4) void k_conv(
    const uint_t* __restrict__ hpk, const uint_t* __restrict__ hn1c,
    const uint_t* __restrict__ Wn2m, const float* __restrict__ nbias,
    const int* __restrict__ rps, const int* __restrict__ esd,
    float* __restrict__ aggr) {
  __shared__ uint_t Gp[NPB * GSTR];        // 32 KB
  __shared__ int2 eStage[ECREG];           // 768 B
  const int tid = threadIdx.x;
  const int w = tid >> 6, lane = tid & 63;
  const int q = lane >> 4, n16 = lane & 15;
  const int half = blockIdx.x / 625;
  const int ng = blockIdx.x - half * 625;
  const int n0 = ng * NPB;
  const int e0 = rps[n0], e1 = rps[n0 + NPB];
  const int ecnt = e1 - e0;

  if (tid < ECREG && tid < ecnt) eStage[tid] = ((const int2*)esd)[e0 + tid];

  FragU a0, a1;
  {
    const uint4* ap = (const uint4*)(hpk + (size_t)(n0 + n16) * 32);
    a0.u = ap[q];
    a1.u = ap[4 + q];
  }
  __syncthreads();  // eStage visible

  float acc[ESLOT];
#pragma unroll
  for (int s = 0; s < ESLOT; ++s) {
    const int li = w * ESLOT + s;
    float v = 0.f;
    if (half == 0 && li < ecnt)
      v = nbias[(size_t)eStage[li].x * 64 + lane];
    acc[s] = v;
  }

  const int p = w & 3, fh = w >> 2;
  const int wkq = p >> 1, slot2 = (p & 1) * 2;
  for (int cc = 0; cc < CPB; ++cc) {
    const int c = half * CPB + cc;
    if (cc) __syncthreads();
    // ---- phase 1 ----
#pragma unroll
    for (int fi = 0; fi < 2; ++fi) {
      const int fc = fh * 2 + fi;
      uint_t pk[2][4];
#pragma unroll
      for (int kk = 0; kk < 2; ++kk) {
        const int kpg = c * 8 + 2 * p + kk;
        const uint4* bp = (const uint4*)Wn2m + (size_t)(kpg * 4 + fc) * 256 + lane;
        FragU b00, b01, b10, b11;
        b00.u = bp[0];    // par0 hf0
        b01.u = bp[64];   // par0 hf1
        b10.u = bp[128];  // par1 hf0
        b11.u = bp[192];  // par1 hf1
        f32x4_t acc0 = {0.f, 0.f, 0.f, 0.f};
        f32x4_t acc1 = {0.f, 0.f, 0.f, 0.f};
        acc0 = __builtin_amdgcn_mfma_f32_16x16x32_bf16(a0.b, b00.b, acc0, 0, 0, 0);
        acc0 = __builtin_amdgcn_mfma_f32_16x16x32_bf16(a1.b, b01.b, acc0, 0, 0, 0);
        acc1 = __builtin_amdgcn_mfma_f32_16x16x32_bf16(a0.b, b10.b, acc1, 0, 0, 0);
        acc1 = __builtin_amdgcn_mfma_f32_16x16x32_bf16(a1.b, b11.b, acc1, 0, 0, 0);
#pragma unroll
        for (int r = 0; r < 4; ++r)
          pk[kk][r] = pack2(acc0[r], acc1[r]);
      }
#pragma unroll
      for (int r = 0; r < 4; ++r) {
        const int m = q * 4 + r;
        uint2 v; v.x = pk[0][r]; v.y = pk[1][r];
        *(uint2*)&Gp[(size_t)m * GSTR + (wkq * 64 + fc * 16 + n16) * 4 + slot2] = v;
      }
    }
    __syncthreads();
    // ---- phase 2: contiguous slots, src-dedup G reads ----
    int prev_src = -1;
    uint4 g0, g1;
#pragma unroll
    for (int s = 0; s < ESLOT; ++s) {
      const int li = w * ESLOT + s;
      if (li < ecnt) {
        const int2 sd = eStage[li];
        if (sd.x != prev_src) {  // wave-uniform branch
          prev_src = sd.x;
          const uint4* gb = (const uint4*)Gp + (size_t)(prev_src - n0) * (GSTR / 4) + lane;
          g0 = gb[0];
          g1 = gb[64];
        }
        const uint4* hp = (const uint4*)(hn1c + ((size_t)c * EE + e0 + li) * 8);
        uint4 hv0 = hp[0], hv1 = hp[1];
        float pt = acc[s];
        pt = dot2a(g0.x, hv0.x, pt);
        pt = dot2a(g0.y, hv0.y, pt);
        pt = dot2a(g0.z, hv0.z, pt);
        pt = dot2a(g0.w, hv0.w, pt);
        pt = dot2a(g1.x, hv1.x, pt);
        pt = dot2a(g1.y, hv1.y, pt);
        pt = dot2a(g1.z, hv1.z, pt);
        pt = dot2a(g1.w, hv1.w, pt);
        acc[s] = pt;
      }
    }
    // overflow edges (virtually never): per-chunk atomic path
    for (int li = ECREG + w; li < ecnt; li += 8) {
      const int ii = e0 + li;
      const int src = __builtin_amdgcn_readfirstlane(esd[2 * ii]);
      const int dst = __builtin_amdgcn_readfirstlane(esd[2 * ii + 1]);
      const int m = src - n0;
      float pt = (half == 0 && cc == 0) ? nbias[(size_t)src * 64 + lane] : 0.f;
      const uint4* hp = (const uint4*)(hn1c + ((size_t)c * EE + ii) * 8);
      uint4 hv0 = hp[0], hv1 = hp[1];
      const uint4* gb = (const uint4*)Gp + (size_t)m * (GSTR / 4) + lane;
      uint4 og0 = gb[0], og1 = gb[64];
      pt = dot2a(og0.x, hv0.x, pt);
      pt = dot2a(og0.y, hv0.y, pt);
      pt = dot2a(og0.z, hv0.z, pt);
      pt = dot2a(og0.w, hv0.w, pt);
      pt = dot2a(og1.x, hv1.x, pt);
      pt = dot2a(og1.y, hv1.y, pt);
      pt = dot2a(og1.z, hv1.z, pt);
      pt = dot2a(og1.w, hv1.w, pt);
      atomicAdd(&aggr[(size_t)dst * 64 + lane], pt);
    }
  }
  // ---- commit: one atomic per register-tracked edge ----
#pragma unroll
  for (int s = 0; s < ESLOT; ++s) {
    const int li = w * ESLOT + s;
    if (li < ecnt) {
      const int dst = eStage[li].y;
      atomicAdd(&aggr[(size_t)dst * 64 + lane], acc[s]);
    }
  }
}

// ---------------- h update: 4 nodes/block; fp32 canonical weights; re-zeros aggr ----------------
__global__ __launch_bounds__(256) void k_update(
    float* __restrict__ h, uint_t* __restrict__ hpk,
    float* __restrict__ aggr, const float* __restrict__ bn2,
    const float* __restrict__ root, const float* __restrict__ cb,
    float* __restrict__ nbias, int l) {
  __shared__ float hl[4][DD];
  __shared__ float al[4][DD];
  const int tid = threadIdx.x, w = tid >> 6, f = tid & 63;
  const int n = blockIdx.x * 4 + w;
  float hv = h[(size_t)n * DD + f];
  hl[w][f] = hv;
  float acc = hv + aggr[(size_t)n * DD + f] + cb[l * DD + f];
  aggr[(size_t)n * DD + f] = 0.f;
  __syncthreads();
  const float* rp = root + (size_t)l * DD2;
#pragma unroll
  for (int d = 0; d < DD; ++d) acc += hl[w][d] * rp[d * DD + f];
  h[(size_t)n * DD + f] = acc;
  al[w][f] = acc;
  float other = __shfl_down(acc, 1);
  if ((f & 1) == 0)
    hpk[(size_t)n * 32 + (f >> 1)] = pack2(acc, other);
  __syncthreads();
  float nb = 0.f;
#pragma unroll
  for (int d = 0; d < DD; ++d) nb += al[w][d] * bn2[d * DD + f];
  nbias[(size_t)n * DD + f] = nb;
}

// ---------------- fused Set2Set (3x LSTM+attention) + output MLP ----------------
#define EVCAP 512
__global__ void k_s2s(const float* __restrict__ h, const int* __restrict__ goff,
                      const float* __restrict__ Wiht, const float* __restrict__ Whht,
                      const float* __restrict__ lb,
                      const float* __restrict__ Wo1, const float* __restrict__ bo1,
                      const float* __restrict__ Wo2, const float* __restrict__ bo2,
                      void* __restrict__ outv, const int* __restrict__ flag) {
  __shared__ float qsl[K1];
  __shared__ float hsl[DD];
  __shared__ float csl[DD];
  __shared__ float gl[4][DD];
  __shared__ float red[256];
  __shared__ float ev[EVCAP];
  __shared__ float rp4[4][DD];
  const int g = blockIdx.x, tid = threadIdx.x;

  if (tid < K1) qsl[tid] = 0.f;
  else if (tid < K1 + DD) hsl[tid - K1] = 0.f;
  else csl[tid - K1 - DD] = 0.f;
  __syncthreads();

  const int i0 = goff[g];
  int cnt = goff[g + 1] - i0;
  if (cnt > EVCAP) cnt = EVCAP;  // never triggers (mean 19.5/graph)

  for (int m = 0; m < MM; ++m) {
    {
      float a = lb[tid];
      for (int i = 0; i < K1; ++i) a += qsl[i] * Wiht[i * 256 + tid];
      for (int i = 0; i < DD; ++i) a += hsl[i] * Whht[i * 256 + tid];
      gl[tid >> 6][tid & 63] = a;
    }
    __syncthreads();
    if (tid < DD) {
      float ig = sigmf_(gl[0][tid]), fg = sigmf_(gl[1][tid]);
      float gg = tanhf(gl[2][tid]), og = sigmf_(gl[3][tid]);
      float c = fg * csl[tid] + ig * gg;
      csl[tid] = c;
      hsl[tid] = og * tanhf(c);
    }
    __syncthreads();
    float lmax = -1e30f;
    for (int jj = tid; jj < cnt; jj += 256) {
      const float* hp = h + (size_t)(i0 + jj) * DD;
      float e = 0.f;
#pragma unroll
      for (int d = 0; d < DD; ++d) e += hp[d] * hsl[d];
      ev[jj] = e;
      lmax = fmaxf(lmax, e);
    }
    red[tid] = lmax;
    __syncthreads();
    for (int s = 128; s > 0; s >>= 1) {
      if (tid < s) red[tid] = fmaxf(red[tid], red[tid + s]);
      __syncthreads();
    }
    const float emax = red[0];
    __syncthreads();
    float lsum = 0.f;
    for (int jj = tid; jj < cnt; jj += 256) {
      float ex = expf(ev[jj] - emax);
      ev[jj] = ex;
      lsum += ex;
    }
    red[tid] = lsum;
    __syncthreads();
    for (int s = 128; s > 0; s >>= 1) {
      if (tid < s) red[tid] += red[tid + s];
      __syncthreads();
    }
    const float denom = red[0];
    const int f = tid & 63, grp = tid >> 6;
    float acc = 0.f;
    for (int jj = grp; jj < cnt; jj += 4)
      acc += ev[jj] * h[(size_t)(i0 + jj) * DD + f];
    rp4[grp][f] = acc;
    __syncthreads();
    if (tid < DD) {
      float r = rp4[0][tid] + rp4[1][tid] + rp4[2][tid] + rp4[3][tid];
      r = (cnt > 0 && denom > 0.f) ? r / denom : 0.f;
      qsl[tid] = hsl[tid];
      qsl[DD + tid] = r;
    }
    __syncthreads();
  }
  if (tid < DD) {
    float t = bo1[tid];
    for (int i = 0; i < K1; ++i) t += qsl[i] * Wo1[i * DD + tid];
    float s = siluf_(t) * Wo2[tid];
    for (int off = 32; off > 0; off >>= 1) s += __shfl_down(s, off);
    if (tid == 0) {
      float v = s + bo2[0];
      if (*flag) ((ushort_t*)outv)[g] = f2bf(v);
      else       ((float*)outv)[g] = v;
    }
  }
}

extern "C" void kernel_launch(void* const* d_in, const int* in_sizes, int n_in,
                              void* d_out, int out_size, void* d_ws, size_t ws_size,
                              hipStream_t stream) {
  const void* x_r    = d_in[0];
  const int*  ei     = (const int*)d_in[1];
  const void* ea_r   = d_in[2];
  const int*  batch  = (const int*)d_in[3];
  const void* W0_r   = d_in[4];
  const void* b0_r   = d_in[5];
  const void* Wn1_r  = d_in[6];
  const void* bn1_r  = d_in[7];
  const void* Wn2_r  = d_in[8];
  const void* bn2_r  = d_in[9];
  const void* root_r = d_in[10];
  const void* cb_r   = d_in[11];
  const void* Wih_r  = d_in[12];
  const void* Whh_r  = d_in[13];
  const void* lb_r   = d_in[14];
  const void* Wo1_r  = d_in[15];
  const void* bo1_r  = d_in[16];
  const void* Wo2_r  = d_in[17];
  const void* bo2_r  = d_in[18];

  char* w = (char*)d_ws;
  size_t off = 0;
  auto alloc = [&](size_t bytes) -> void* {
    void* p = w + off;
    off = (off + bytes + 255) & ~(size_t)255;
    return p;
  };
  int* flag = (int*)alloc(4);
  float* xc    = (float*)alloc((size_t)NN * DIN_ * 4);
  float* eac   = (float*)alloc((size_t)EE * 4 * 4);
  float* W0c   = (float*)alloc((size_t)DIN_ * DD * 4);
  float* b0c   = (float*)alloc((size_t)DD * 4);
  float* Wn1c  = (float*)alloc((size_t)4 * K1 * 4);
  float* bn1c  = (float*)alloc((size_t)K1 * 4);
  float* bn2c  = (float*)alloc((size_t)DD2 * 4);
  float* rootc = (float*)alloc((size_t)LL * DD2 * 4);
  float* cbc   = (float*)alloc((size_t)LL * DD * 4);
  float* Wihc  = (float*)alloc((size_t)4 * DD * K1 * 4);
  float* Whhc  = (float*)alloc((size_t)4 * DD * DD * 4);
  float* lbc   = (float*)alloc((size_t)4 * DD * 4);
  float* Wo1c  = (float*)alloc((size_t)K1 * DD * 4);
  float* bo1c  = (float*)alloc((size_t)DD * 4);
  float* Wo2c  = (float*)alloc((size_t)DD * 4);
  float* bo2c  = (float*)alloc((size_t)4);
  float* Wiht  = (float*)alloc((size_t)K1 * 256 * 4);
  float* Whht  = (float*)alloc((size_t)DD * 256 * 4);
  uint_t* Wn2m = (uint_t*)alloc((size_t)64 * 4 * 2 * 2 * 64 * 4 * 4);  // 1 MB
  float*  h    = (float*)alloc((size_t)NN * DD * 4);
  uint_t* hpk  = (uint_t*)alloc((size_t)NN * 32 * 4);
  uint_t* hn1c = (uint_t*)alloc((size_t)EE * (K1 / 2) * 4);  // chunk-major
  float*  aggr = (float*)alloc((size_t)NN * DD * 4);
  float*  nbias= (float*)alloc((size_t)NN * DD * 4);
  int* cnts  = (int*)alloc((size_t)2 * NN * 4);
  int* rps   = (int*)alloc((size_t)(NN + 1) * 4);
  int* epos  = (int*)alloc((size_t)EE * 4);
  int* esd   = (int*)alloc((size_t)2 * EE * 4);
  int* goff  = (int*)alloc((size_t)(BB + 1) * 4);

  int* cnt_s = cnts;
  int* cur_s = cnts + NN;

  hipMemsetAsync(cnts, 0, (size_t)2 * NN * 4, stream);
  hipMemsetAsync(aggr, 0, (size_t)NN * DD * 4, stream);

  CanonArgs ca;
  const void* srcs[NCANON] = {x_r, ea_r, W0_r, b0_r, Wn1_r, bn1_r, bn2_r, root_r,
                              cb_r, Wih_r, Whh_r, lb_r, Wo1_r, bo1_r, Wo2_r, bo2_r};
  float* dsts[NCANON] = {xc, eac, W0c, b0c, Wn1c, bn1c, bn2c, rootc,
                         cbc, Wihc, Whhc, lbc, Wo1c, bo1c, Wo2c, bo2c};
  int cnts_c[NCANON] = {NN * DIN_, EE * 4, DIN_ * DD, DD, 4 * K1, K1, DD2, LL * DD2,
                        LL * DD, 4 * DD * K1, 4 * DD * DD, 4 * DD, K1 * DD, DD, DD, 1};
  for (int i = 0; i < NCANON; ++i) { ca.src[i] = srcs[i]; ca.dst[i] = dsts[i]; ca.n[i] = cnts_c[i]; }
  {
    dim3 grid((EE * 4 + 255) / 256, NCANON);
    k_canon<<<grid, 256, 0, stream>>>(ca, (const ushort_t*)ea_r, flag);
  }
  k_wn2m<<<K1, 256, 0, stream>>>(Wn2_r, Wn2m, flag);
  k_wT<<<(4 * DD * K1 + 255) / 256, 256, 0, stream>>>(Wihc, Whhc, Wiht, Whht);

  k_embed<<<NN / 4, 256, 0, stream>>>(xc, W0c, b0c, bn2c, h, hpk, nbias);
  k_hist<<<(EE + 255) / 256, 256, 0, stream>>>(ei, cnt_s);
  k_scan<<<2, 1024, 0, stream>>>(cnt_s, rps, batch, goff);
  k_fill<<<(EE + 255) / 256, 256, 0, stream>>>(ei, rps, cur_s, epos, esd);
  k_edgemlp<<<(EE * (K1 / 2) + 255) / 256, 256, 0, stream>>>(eac, Wn1c, bn1c, epos, hn1c);

  for (int l = 0; l < LL; ++l) {
    k_conv<<<CSPL * (NN / NPB), 512, 0, stream>>>(hpk, hn1c, Wn2m, nbias, rps, esd, aggr);
    k_update<<<NN / 4, 256, 0, stream>>>(h, hpk, aggr, bn2c, rootc, cbc, nbias, l);
  }

  k_s2s<<<BB, 256, 0, stream>>>(h, goff, Wiht, Whht, lbc, Wo1c, bo1c, Wo2c, bo2c,
                                d_out, flag);
}

// Round 16
// 465.094 us; speedup vs baseline: 1.5188x; 1.0400x over previous
//
#include <hip/hip_runtime.h>
#include <cstdint>
#include <cstddef>

#define NN   10000
#define EE   40000
#define DIN_ 11
#define DD   64
#define LL   4
#define BB   512
#define MM   3
#define K1   128   // 2*D
#define DD2  4096  // D*D
#define NPB  16    // nodes per k_conv block
#define NCH  8     // total K-chunks (8 bf16-pairs each)
#define CSPL 2     // chunk-split across blocks
#define CPB  4     // chunks per block = NCH / CSPL
#define ESLOT 12   // register-accumulated edge slots per wave
#define ECREG (8 * ESLOT)  // 96 register-tracked edges per block

typedef unsigned short ushort_t;
typedef unsigned int   uint_t;

typedef __bf16 bf16x8_t __attribute__((ext_vector_type(8)));
typedef float  f32x4_t  __attribute__((ext_vector_type(4)));
union FragU { uint4 u; bf16x8_t b; };

__device__ __forceinline__ float bfu(ushort_t u) { return __uint_as_float(((uint_t)u) << 16); }
__device__ __forceinline__ float bflo(uint_t u) { return __uint_as_float(u << 16); }
__device__ __forceinline__ float bfhi(uint_t u) { return __uint_as_float(u & 0xffff0000u); }
__device__ __forceinline__ ushort_t f2bf(float f) {
  uint_t u = __float_as_uint(f);
  u = (u + 0x7fffu + ((u >> 16) & 1u)) >> 16;
  return (ushort_t)u;
}
__device__ __forceinline__ uint_t pack2(float lo, float hi) {
  return (uint_t)f2bf(lo) | ((uint_t)f2bf(hi) << 16);
}
__device__ __forceinline__ float sigmf_(float x) { return 1.f / (1.f + expf(-x)); }
__device__ __forceinline__ float siluf_(float x) { return x / (1.f + expf(-x)); }

#if defined(__HIP_DEVICE_COMPILE__) && __has_builtin(__builtin_amdgcn_fdot2_f32_bf16)
typedef __bf16 bf16x2_t __attribute__((ext_vector_type(2)));
__device__ __forceinline__ float dot2a(uint_t a, uint_t b, float c) {
  union { uint_t u; bf16x2_t v; } ua, ub;
  ua.u = a; ub.u = b;
  return __builtin_amdgcn_fdot2_f32_bf16(ua.v, ub.v, c, false);
}
#else
__device__ __forceinline__ float dot2a(uint_t a, uint_t b, float c) {
  return c + bflo(a) * bflo(b) + bfhi(a) * bfhi(b);
}
#endif

// ---------------- canonicalize float inputs to fp32 (self-detecting dtype) ----------------
// edge_attr is uniform[0,1): if bf16, every ushort has sign=0 and value <= 0x3F80.
// Each block re-derives the flag from the same 256 ushorts (deterministic); block (0,0)
// publishes it for later kernels.
#define NCANON 16
struct CanonArgs {
  const void* src[NCANON];
  float* dst[NCANON];
  int n[NCANON];
};
__global__ void k_canon(CanonArgs a, const ushort_t* __restrict__ ea, int* __restrict__ flag) {
  __shared__ int bad;
  if (threadIdx.x == 0) bad = 0;
  __syncthreads();
  ushort_t u = ea[threadIdx.x];
  if ((u & 0x8000u) || u > 0x3F80u) atomicAdd(&bad, 1);
  __syncthreads();
  const int isbf = (bad == 0) ? 1 : 0;
  if (blockIdx.x == 0 && blockIdx.y == 0 && threadIdx.x == 0) *flag = isbf;
  const int ai = blockIdx.y;
  const int n = a.n[ai];
  const int i = blockIdx.x * 256 + threadIdx.x;
  if (i >= n) return;
  float v;
  if (isbf) v = bfu(((const ushort_t*)a.src[ai])[i]);
  else      v = ((const float*)a.src[ai])[i];
  a.dst[ai][i] = v;
}

// ---------------- Wn2 repack into MFMA B-fragment order (coalesced) ----------------
// out uint index: ((((kpg*4+fc)*2+par)*2+hf)*64 + lane)*4 + jp
//   element = Wn2[2*kpg+par][(hf*32 + (lane>>4)*8 + 2*jp (+1))*64 + fc*16 + (lane&15)]
__global__ void k_wn2m(const void* __restrict__ Wn2, uint_t* __restrict__ out,
                       const int* __restrict__ flag) {
  __shared__ ushort_t row[DD2];  // 8 KB
  const int k = blockIdx.x, tid = threadIdx.x;
  if (*flag) {
    const uint4* src = (const uint4*)((const ushort_t*)Wn2 + (size_t)k * DD2);
    ((uint4*)row)[tid] = src[tid];
    ((uint4*)row)[tid + 256] = src[tid + 256];
  } else {
    const float* src = (const float*)Wn2 + (size_t)k * DD2;
    for (int j = 0; j < 16; ++j) row[tid + 256 * j] = f2bf(src[tid + 256 * j]);
  }
  __syncthreads();
  const int kpg = k >> 1, par = k & 1;
  const int lane = tid >> 2, jp = tid & 3;
  const int q = lane >> 4, n = lane & 15;
  for (int fc = 0; fc < 4; ++fc) {
#pragma unroll
    for (int hf = 0; hf < 2; ++hf) {
      int d0 = hf * 32 + q * 8 + 2 * jp;
      int f = fc * 16 + n;
      uint_t lo = row[d0 * 64 + f], hi = row[(d0 + 1) * 64 + f];
      out[((((size_t)kpg * 4 + fc) * 2 + par) * 2 + hf) * 256 + tid] = lo | (hi << 16);
    }
  }
}

// ---------------- LSTM weight transpose: Wiht[i][j], Whht[i][j] ----------------
__global__ void k_wT(const float* __restrict__ Wihc, const float* __restrict__ Whhc,
                     float* __restrict__ Wiht, float* __restrict__ Whht) {
  int idx = blockIdx.x * 256 + threadIdx.x;
  if (idx < 4 * DD * K1) {
    int j = idx >> 7, i = idx & 127;  // Wihc[j][i]
    Wiht[i * 256 + j] = Wihc[idx];
  }
  if (idx < 4 * DD * DD) {
    int j = idx >> 6, i = idx & 63;   // Whhc[j][i]
    Whht[i * 256 + j] = Whhc[idx];
  }
}

// ---------------- node embed: h, hpk, nbias ----------------
__global__ void k_embed(const float* __restrict__ x, const float* __restrict__ W0,
                        const float* __restrict__ b0, const float* __restrict__ bn2,
                        float* __restrict__ h, uint_t* __restrict__ hpk,
                        float* __restrict__ nbias) {
  __shared__ float xs[DIN_];
  __shared__ float hl[DD];
  const int n = blockIdx.x, f = threadIdx.x;
  if (f < DIN_) xs[f] = x[n * DIN_ + f];
  __syncthreads();
  float a = b0[f];
  for (int i = 0; i < DIN_; ++i) a += xs[i] * W0[i * DD + f];
  h[(size_t)n * DD + f] = a;
  hl[f] = a;
  float other = __shfl_down(a, 1);
  if ((f & 1) == 0)
    hpk[(size_t)n * 32 + (f >> 1)] = pack2(a, other);
  __syncthreads();
  float nb = 0.f;
#pragma unroll
  for (int d = 0; d < DD; ++d) nb += hl[d] * bn2[d * DD + f];
  nbias[(size_t)n * DD + f] = nb;
}

// ---------------- edge MLP layer1 -> hn1c, chunk-major CSR order ----------------
// hn1c[((j>>3)*EE + pos)*8 + (j&7)] : chunk c holds pairs c*8..c*8+7 of each edge.
__global__ void k_edgemlp(const float* __restrict__ ea, const float* __restrict__ Wn1,
                          const float* __restrict__ bn1, const int* __restrict__ epos,
                          uint_t* __restrict__ hn1c) {
  int idx = blockIdx.x * 256 + threadIdx.x;  // e*64 + j
  if (idx >= EE * (K1 / 2)) return;
  int e = idx >> 6, j = idx & 63;
  int k0 = 2 * j, k1 = 2 * j + 1;
  float a0 = ea[e * 4 + 0], a1 = ea[e * 4 + 1], a2 = ea[e * 4 + 2], a3 = ea[e * 4 + 3];
  float t0 = bn1[k0] + a0 * Wn1[k0] + a1 * Wn1[K1 + k0] + a2 * Wn1[2 * K1 + k0] + a3 * Wn1[3 * K1 + k0];
  float t1 = bn1[k1] + a0 * Wn1[k1] + a1 * Wn1[K1 + k1] + a2 * Wn1[2 * K1 + k1] + a3 * Wn1[3 * K1 + k1];
  int pos = epos[e];
  hn1c[((size_t)(j >> 3) * EE + pos) * 8 + (j & 7)] = pack2(siluf_(t0), siluf_(t1));
}

// ---------------- src-CSR build ----------------
__global__ void k_hist(const int* __restrict__ ei, int* __restrict__ cnt_s) {
  int e = blockIdx.x * 256 + threadIdx.x;
  if (e >= EE) return;
  atomicAdd(&cnt_s[ei[e]], 1);
}

// block 0: exclusive scan of cnt -> rp; block 1: goff from sorted batch
__global__ void k_scan(const int* __restrict__ cnt, int* __restrict__ rp,
                       const int* __restrict__ batch, int* __restrict__ goff) {
  if (blockIdx.x == 1) {
    int g = threadIdx.x;
    if (g > BB) return;
    int lo = 0, hi = NN;
    while (lo < hi) {
      int mid = (lo + hi) >> 1;
      if (batch[mid] < g) lo = mid + 1; else hi = mid;
    }
    goff[g] = lo;
    return;
  }
  __shared__ int part[1024];
  const int tid = threadIdx.x;
  const int chunk = (NN + 1023) / 1024;
  int s = 0;
  for (int j = 0; j < chunk; ++j) {
    int idx = tid * chunk + j;
    if (idx < NN) s += cnt[idx];
  }
  part[tid] = s;
  __syncthreads();
  for (int off = 1; off < 1024; off <<= 1) {
    int v = (tid >= off) ? part[tid - off] : 0;
    __syncthreads();
    part[tid] += v;
    __syncthreads();
  }
  int base = (tid == 0) ? 0 : part[tid - 1];
  for (int j = 0; j < chunk; ++j) {
    int idx = tid * chunk + j;
    if (idx < NN) { rp[idx] = base; base += cnt[idx]; }
  }
  if (tid == 1023) rp[NN] = part[1023];
}

// epos[e] = CSR slot of edge e; esd[2*pos..] = (src, dst)
__global__ void k_fill(const int* __restrict__ ei, const int* __restrict__ rps,
                       int* __restrict__ cur_s, int* __restrict__ epos,
                       int* __restrict__ esd) {
  int e = blockIdx.x * 256 + threadIdx.x;
  if (e >= EE) return;
  int s = ei[e], d = ei[EE + e];
  int ps = atomicAdd(&cur_s[s], 1);
  int pos = rps[s] + ps;
  epos[e] = pos;
  esd[2 * pos] = s;
  esd[2 * pos + 1] = d;
}

// ---------------- fused NNConv message kernel ----------------
// Grid: CSPL*625, 512 threads. half = bx/625 (K halves), ng = bx%625 (node group).
// Block serializes CPB=4 chunks of 8 kp. Per chunk: wave w computes kp w via MFMA
// into 32 KB LDS; then each wave updates its register-resident edge partials
// (acc[ESLOT], edges strided by 8). ONE atomicAdd per edge per half at the end.
// launch_bounds (512,4): 128-VGPR budget so acc[] stays in registers (a (512,8)
// bound forces a 64-VGPR cap -> scratch spills -> 300 MB/layer of spill traffic).
__global__ __launch_bounds__(512, 4) void k_conv(
    const uint_t* __restrict__ hpk, const uint_t* __restrict__ hn1c,
    const uint_t* __restrict__ Wn2m, const float* __restrict__ nbias,
    const int* __restrict__ rps, const int* __restrict__ esd,
    float* __restrict__ aggr) {
  __shared__ uint_t Gp[NPB * 2 * 64 * 4];  // 32 KB: ((m*2+kq)*64+f)*4 + slot
  __shared__ int2 eStage[ECREG];           // 768 B
  const int tid = threadIdx.x;
  const int w = tid >> 6, lane = tid & 63;
  const int q = lane >> 4, n16 = lane & 15;
  const int half = blockIdx.x / 625;
  const int ng = blockIdx.x - half * 625;
  const int n0 = ng * NPB;
  const int e0 = rps[n0], e1 = rps[n0 + NPB];
  const int ecnt = e1 - e0;

  if (tid < ECREG && tid < ecnt) eStage[tid] = ((const int2*)esd)[e0 + tid];

  FragU a0, a1;
  {
    const uint4* ap = (const uint4*)(hpk + (size_t)(n0 + n16) * 32);
    a0.u = ap[q];
    a1.u = ap[4 + q];
  }
  __syncthreads();  // eStage visible

  // seed register accumulators (nbias on half 0)
  float acc[ESLOT];
#pragma unroll
  for (int s = 0; s < ESLOT; ++s) {
    const int li = w + 8 * s;
    float v = 0.f;
    if (half == 0 && li < ecnt && li < ECREG)
      v = nbias[(size_t)eStage[li].x * 64 + lane];
    acc[s] = v;
  }

  const int kq = w >> 2, slot = w & 3;
  for (int cc = 0; cc < CPB; ++cc) {
    const int c = half * CPB + cc;
    if (cc) __syncthreads();  // prior phase-2 reads done
    // ---- phase 1: wave w computes chunk-local kp = w ----
    const int kpg = c * 8 + w;
    for (int fc = 0; fc < 4; ++fc) {
      const uint4* bp = (const uint4*)Wn2m + (size_t)(kpg * 4 + fc) * 256 + lane;
      FragU b00, b01, b10, b11;
      b00.u = bp[0];    // par0 hf0
      b01.u = bp[64];   // par0 hf1
      b10.u = bp[128];  // par1 hf0
      b11.u = bp[192];  // par1 hf1
      f32x4_t acc0 = {0.f, 0.f, 0.f, 0.f};
      f32x4_t acc1 = {0.f, 0.f, 0.f, 0.f};
      acc0 = __builtin_amdgcn_mfma_f32_16x16x32_bf16(a0.b, b00.b, acc0, 0, 0, 0);
      acc0 = __builtin_amdgcn_mfma_f32_16x16x32_bf16(a1.b, b01.b, acc0, 0, 0, 0);
      acc1 = __builtin_amdgcn_mfma_f32_16x16x32_bf16(a0.b, b10.b, acc1, 0, 0, 0);
      acc1 = __builtin_amdgcn_mfma_f32_16x16x32_bf16(a1.b, b11.b, acc1, 0, 0, 0);
#pragma unroll
      for (int r = 0; r < 4; ++r) {
        const int m = q * 4 + r;  // D row = node index
        Gp[(((m * 2 + kq) * 64 + fc * 16 + n16) * 4 + slot)] = pack2(acc0[r], acc1[r]);
      }
    }
    __syncthreads();
    // ---- phase 2: register-resident edge partials ----
#pragma unroll
    for (int s = 0; s < ESLOT; ++s) {
      const int li = w + 8 * s;
      if (li < ecnt && li < ECREG) {
        const int2 sd = eStage[li];
        const int m = sd.x - n0;
        const uint4* hp = (const uint4*)(hn1c + ((size_t)c * EE + e0 + li) * 8);
        uint4 hv0 = hp[0], hv1 = hp[1];
        const uint4* gb = (const uint4*)Gp + (size_t)(m * 2) * 64 + lane;
        uint4 g0 = gb[0], g1 = gb[64];
        float p = acc[s];
        p = dot2a(g0.x, hv0.x, p);
        p = dot2a(g0.y, hv0.y, p);
        p = dot2a(g0.z, hv0.z, p);
        p = dot2a(g0.w, hv0.w, p);
        p = dot2a(g1.x, hv1.x, p);
        p = dot2a(g1.y, hv1.y, p);
        p = dot2a(g1.z, hv1.z, p);
        p = dot2a(g1.w, hv1.w, p);
        acc[s] = p;
      }
    }
    // overflow edges (virtually never): per-chunk atomic path
    for (int li = ECREG + w; li < ecnt; li += 8) {
      const int ii = e0 + li;
      const int src = __builtin_amdgcn_readfirstlane(esd[2 * ii]);
      const int dst = __builtin_amdgcn_readfirstlane(esd[2 * ii + 1]);
      const int m = src - n0;
      float p = (half == 0 && cc == 0) ? nbias[(size_t)src * 64 + lane] : 0.f;
      const uint4* hp = (const uint4*)(hn1c + ((size_t)c * EE + ii) * 8);
      uint4 hv0 = hp[0], hv1 = hp[1];
      const uint4* gb = (const uint4*)Gp + (size_t)(m * 2) * 64 + lane;
      uint4 g0 = gb[0], g1 = gb[64];
      p = dot2a(g0.x, hv0.x, p);
      p = dot2a(g0.y, hv0.y, p);
      p = dot2a(g0.z, hv0.z, p);
      p = dot2a(g0.w, hv0.w, p);
      p = dot2a(g1.x, hv1.x, p);
      p = dot2a(g1.y, hv1.y, p);
      p = dot2a(g1.z, hv1.z, p);
      p = dot2a(g1.w, hv1.w, p);
      atomicAdd(&aggr[(size_t)dst * 64 + lane], p);
    }
  }
  // ---- commit: one atomic per register-tracked edge ----
#pragma unroll
  for (int s = 0; s < ESLOT; ++s) {
    const int li = w + 8 * s;
    if (li < ecnt && li < ECREG) {
      const int dst = eStage[li].y;
      atomicAdd(&aggr[(size_t)dst * 64 + lane], acc[s]);
    }
  }
}

// ---------------- h update: 4 nodes/block; residual + aggr + root GEMM; re-zeros aggr ----------------
__global__ __launch_bounds__(256) void k_update(
    float* __restrict__ h, uint_t* __restrict__ hpk,
    float* __restrict__ aggr, const float* __restrict__ bn2,
    const float* __restrict__ root, const float* __restrict__ cb,
    float* __restrict__ nbias, int l) {
  __shared__ float hl[4][DD];
  __shared__ float al[4][DD];
  const int tid = threadIdx.x, w = tid >> 6, f = tid & 63;
  const int n = blockIdx.x * 4 + w;
  float hv = h[(size_t)n * DD + f];
  hl[w][f] = hv;
  float acc = hv + aggr[(size_t)n * DD + f] + cb[l * DD + f];
  aggr[(size_t)n * DD + f] = 0.f;
  __syncthreads();
  const float* rp = root + (size_t)l * DD2;
#pragma unroll
  for (int d = 0; d < DD; ++d) acc += hl[w][d] * rp[d * DD + f];
  h[(size_t)n * DD + f] = acc;
  al[w][f] = acc;
  float other = __shfl_down(acc, 1);
  if ((f & 1) == 0)
    hpk[(size_t)n * 32 + (f >> 1)] = pack2(acc, other);
  __syncthreads();
  float nb = 0.f;
#pragma unroll
  for (int d = 0; d < DD; ++d) nb += al[w][d] * bn2[d * DD + f];
  nbias[(size_t)n * DD + f] = nb;
}

// ---------------- fused Set2Set (3x LSTM+attention) + output MLP ----------------
#define EVCAP 2048
__global__ void k_s2s(const float* __restrict__ h, const int* __restrict__ goff,
                      const float* __restrict__ Wiht, const float* __restrict__ Whht,
                      const float* __restrict__ lb,
                      const float* __restrict__ Wo1, const float* __restrict__ bo1,
                      const float* __restrict__ Wo2, const float* __restrict__ bo2,
                      void* __restrict__ outv, const int* __restrict__ flag) {
  __shared__ float qsl[K1];
  __shared__ float hsl[DD];
  __shared__ float csl[DD];
  __shared__ float gl[4][DD];
  __shared__ float red[256];
  __shared__ float ev[EVCAP];
  __shared__ float rp4[4][DD];
  const int g = blockIdx.x, tid = threadIdx.x;

  if (tid < K1) qsl[tid] = 0.f;
  else if (tid < K1 + DD) hsl[tid - K1] = 0.f;
  else csl[tid - K1 - DD] = 0.f;
  __syncthreads();

  const int i0 = goff[g];
  int cnt = goff[g + 1] - i0;
  if (cnt > EVCAP) cnt = EVCAP;

  for (int m = 0; m < MM; ++m) {
    {
      float a = lb[tid];
      for (int i = 0; i < K1; ++i) a += qsl[i] * Wiht[i * 256 + tid];
      for (int i = 0; i < DD; ++i) a += hsl[i] * Whht[i * 256 + tid];
      gl[tid >> 6][tid & 63] = a;
    }
    __syncthreads();
    if (tid < DD) {
      float ig = sigmf_(gl[0][tid]), fg = sigmf_(gl[1][tid]);
      float gg = tanhf(gl[2][tid]), og = sigmf_(gl[3][tid]);
      float c = fg * csl[tid] + ig * gg;
      csl[tid] = c;
      hsl[tid] = og * tanhf(c);
    }
    __syncthreads();
    float lmax = -1e30f;
    for (int jj = tid; jj < cnt; jj += 256) {
      const float* hp = h + (size_t)(i0 + jj) * DD;
      float e = 0.f;
#pragma unroll
      for (int d = 0; d < DD; ++d) e += hp[d] * hsl[d];
      ev[jj] = e;
      lmax = fmaxf(lmax, e);
    }
    red[tid] = lmax;
    __syncthreads();
    for (int s = 128; s > 0; s >>= 1) {
      if (tid < s) red[tid] = fmaxf(red[tid], red[tid + s]);
      __syncthreads();
    }
    const float emax = red[0];
    __syncthreads();
    float lsum = 0.f;
    for (int jj = tid; jj < cnt; jj += 256) {
      float ex = expf(ev[jj] - emax);
      ev[jj] = ex;
      lsum += ex;
    }
    red[tid] = lsum;
    __syncthreads();
    for (int s = 128; s > 0; s >>= 1) {
      if (tid < s) red[tid] += red[tid + s];
      __syncthreads();
    }
    const float denom = red[0];
    const int f = tid & 63, grp = tid >> 6;
    float acc = 0.f;
    for (int jj = grp; jj < cnt; jj += 4)
      acc += ev[jj] * h[(size_t)(i0 + jj) * DD + f];
    rp4[grp][f] = acc;
    __syncthreads();
    if (tid < DD) {
      float r = rp4[0][tid] + rp4[1][tid] + rp4[2][tid] + rp4[3][tid];
      r = (cnt > 0 && denom > 0.f) ? r / denom : 0.f;
      qsl[tid] = hsl[tid];
      qsl[DD + tid] = r;
    }
    __syncthreads();
  }
  if (tid < DD) {
    float t = bo1[tid];
    for (int i = 0; i < K1; ++i) t += qsl[i] * Wo1[i * DD + tid];
    float s = siluf_(t) * Wo2[tid];
    for (int off = 32; off > 0; off >>= 1) s += __shfl_down(s, off);
    if (tid == 0) {
      float v = s + bo2[0];
      if (*flag) ((ushort_t*)outv)[g] = f2bf(v);
      else       ((float*)outv)[g] = v;
    }
  }
}

extern "C" void kernel_launch(void* const* d_in, const int* in_sizes, int n_in,
                              void* d_out, int out_size, void* d_ws, size_t ws_size,
                              hipStream_t stream) {
  const void* x_r    = d_in[0];
  const int*  ei     = (const int*)d_in[1];
  const void* ea_r   = d_in[2];
  const int*  batch  = (const int*)d_in[3];
  const void* W0_r   = d_in[4];
  const void* b0_r   = d_in[5];
  const void* Wn1_r  = d_in[6];
  const void* bn1_r  = d_in[7];
  const void* Wn2_r  = d_in[8];
  const void* bn2_r  = d_in[9];
  const void* root_r = d_in[10];
  const void* cb_r   = d_in[11];
  const void* Wih_r  = d_in[12];
  const void* Whh_r  = d_in[13];
  const void* lb_r   = d_in[14];
  const void* Wo1_r  = d_in[15];
  const void* bo1_r  = d_in[16];
  const void* Wo2_r  = d_in[17];
  const void* bo2_r  = d_in[18];

  char* w = (char*)d_ws;
  size_t off = 0;
  auto alloc = [&](size_t bytes) -> void* {
    void* p = w + off;
    off = (off + bytes + 255) & ~(size_t)255;
    return p;
  };
  int* flag = (int*)alloc(4);
  float* xc    = (float*)alloc((size_t)NN * DIN_ * 4);
  float* eac   = (float*)alloc((size_t)EE * 4 * 4);
  float* W0c   = (float*)alloc((size_t)DIN_ * DD * 4);
  float* b0c   = (float*)alloc((size_t)DD * 4);
  float* Wn1c  = (float*)alloc((size_t)4 * K1 * 4);
  float* bn1c  = (float*)alloc((size_t)K1 * 4);
  float* bn2c  = (float*)alloc((size_t)DD2 * 4);
  float* rootc = (float*)alloc((size_t)LL * DD2 * 4);
  float* cbc   = (float*)alloc((size_t)LL * DD * 4);
  float* Wihc  = (float*)alloc((size_t)4 * DD * K1 * 4);
  float* Whhc  = (float*)alloc((size_t)4 * DD * DD * 4);
  float* lbc   = (float*)alloc((size_t)4 * DD * 4);
  float* Wo1c  = (float*)alloc((size_t)K1 * DD * 4);
  float* bo1c  = (float*)alloc((size_t)DD * 4);
  float* Wo2c  = (float*)alloc((size_t)DD * 4);
  float* bo2c  = (float*)alloc((size_t)4);
  float* Wiht  = (float*)alloc((size_t)K1 * 256 * 4);
  float* Whht  = (float*)alloc((size_t)DD * 256 * 4);
  uint_t* Wn2m = (uint_t*)alloc((size_t)64 * 4 * 2 * 2 * 64 * 4 * 4);  // 1 MB
  float*  h    = (float*)alloc((size_t)NN * DD * 4);
  uint_t* hpk  = (uint_t*)alloc((size_t)NN * 32 * 4);
  uint_t* hn1c = (uint_t*)alloc((size_t)EE * (K1 / 2) * 4);  // chunk-major
  float*  aggr = (float*)alloc((size_t)NN * DD * 4);
  float*  nbias= (float*)alloc((size_t)NN * DD * 4);
  int* cnts  = (int*)alloc((size_t)2 * NN * 4);
  int* rps   = (int*)alloc((size_t)(NN + 1) * 4);
  int* epos  = (int*)alloc((size_t)EE * 4);
  int* esd   = (int*)alloc((size_t)2 * EE * 4);
  int* goff  = (int*)alloc((size_t)(BB + 1) * 4);

  int* cnt_s = cnts;
  int* cur_s = cnts + NN;

  hipMemsetAsync(cnts, 0, (size_t)2 * NN * 4, stream);
  hipMemsetAsync(aggr, 0, (size_t)NN * DD * 4, stream);

  CanonArgs ca;
  const void* srcs[NCANON] = {x_r, ea_r, W0_r, b0_r, Wn1_r, bn1_r, bn2_r, root_r,
                              cb_r, Wih_r, Whh_r, lb_r, Wo1_r, bo1_r, Wo2_r, bo2_r};
  float* dsts[NCANON] = {xc, eac, W0c, b0c, Wn1c, bn1c, bn2c, rootc,
                         cbc, Wihc, Whhc, lbc, Wo1c, bo1c, Wo2c, bo2c};
  int cnts_c[NCANON] = {NN * DIN_, EE * 4, DIN_ * DD, DD, 4 * K1, K1, DD2, LL * DD2,
                        LL * DD, 4 * DD * K1, 4 * DD * DD, 4 * DD, K1 * DD, DD, DD, 1};
  for (int i = 0; i < NCANON; ++i) { ca.src[i] = srcs[i]; ca.dst[i] = dsts[i]; ca.n[i] = cnts_c[i]; }
  {
    dim3 grid((EE * 4 + 255) / 256, NCANON);
    k_canon<<<grid, 256, 0, stream>>>(ca, (const ushort_t*)ea_r, flag);
  }
  k_wn2m<<<K1, 256, 0, stream>>>(Wn2_r, Wn2m, flag);
  k_wT<<<(4 * DD * K1 + 255) / 256, 256, 0, stream>>>(Wihc, Whhc, Wiht, Whht);

  k_embed<<<NN, DD, 0, stream>>>(xc, W0c, b0c, bn2c, h, hpk, nbias);
  k_hist<<<(EE + 255) / 256, 256, 0, stream>>>(ei, cnt_s);
  k_scan<<<2, 1024, 0, stream>>>(cnt_s, rps, batch, goff);
  k_fill<<<(EE + 255) / 256, 256, 0, stream>>>(ei, rps, cur_s, epos, esd);
  k_edgemlp<<<(EE * (K1 / 2) + 255) / 256, 256, 0, stream>>>(eac, Wn1c, bn1c, epos, hn1c);

  for (int l = 0; l < LL; ++l) {
    k_conv<<<CSPL * (NN / NPB), 512, 0, stream>>>(hpk, hn1c, Wn2m, nbias, rps, esd, aggr);
    k_update<<<NN / 4, 256, 0, stream>>>(h, hpk, aggr, bn2c, rootc, cbc, nbias, l);
  }

  k_s2s<<<BB, 256, 0, stream>>>(h, goff, Wiht, Whht, lbc, Wo1c, bo1c, Wo2c, bo2c,
                                d_out, flag);
}